// Round 3
// baseline (134.776 us; speedup 1.0000x reference)
//
#include <hip/hip_runtime.h>

#define NS 25
#define NQ 200
#define FG 16
#define FL 64
#define FTOT 80
#define D 512
#define WAY 5
#define MROWS 2000    // 25*80 support rows
#define MPAD 2080     // padded to 13 tiles of 160
#define NROWS 16000   // 200*80 query rows

typedef unsigned char u8;
typedef __attribute__((ext_vector_type(4))) float floatx4;
typedef __attribute__((ext_vector_type(4))) int intx4;
typedef __attribute__((ext_vector_type(8))) int intx8;

__device__ inline void gload_lds16(const void* g, void* l) {
    __builtin_amdgcn_global_load_lds(
        (const __attribute__((address_space(1))) unsigned int*)g,
        (__attribute__((address_space(3))) unsigned int*)l, 16, 0, 0);
}

// One wave per 512-elem row: L2-normalize, cast fp8 e4m3 (OCP), write concat
// layout. Block 4500: zero Sn pad rows + zero out[] + per-class 1/count.
__global__ void normalize_kernel(const float* __restrict__ sg, const float* __restrict__ sl,
                                 const float* __restrict__ qg, const float* __restrict__ ql,
                                 u8* __restrict__ Sn, u8* __restrict__ Qn,
                                 const int* __restrict__ labels,
                                 float* __restrict__ out, float* __restrict__ rcnt) {
    if (blockIdx.x == 4500) {
        intx4 z = {0, 0, 0, 0};
        intx4* pad = (intx4*)(Sn + (size_t)MROWS * D);   // 80 rows * 512 B = 2560 intx4
        for (int i = threadIdx.x; i < (MPAD - MROWS) * D / 16; i += 256) pad[i] = z;
        for (int i = threadIdx.x; i < NQ * WAY; i += 256) out[i] = 0.f;
        if (threadIdx.x == 0) {
            int counts[WAY] = {0, 0, 0, 0, 0};
            for (int s = 0; s < NS; ++s) counts[labels[s]]++;
            for (int c = 0; c < WAY; ++c) rcnt[c] = 1.0f / (float)(counts[c] ? counts[c] : 1);
        }
        return;
    }
    int wave = (blockIdx.x * blockDim.x + threadIdx.x) >> 6;
    int lane = threadIdx.x & 63;
    const int totalRows = MROWS + NROWS;   // 18000
    if (wave >= totalRows) return;

    const float* src;
    u8* dst;
    if (wave < MROWS) {
        int s = wave / FTOT, f = wave % FTOT;
        src = (f < FG) ? sg + (size_t)(s * FG + f) * D
                       : sl + (size_t)(s * FL + (f - FG)) * D;
        dst = Sn + (size_t)wave * D;
    } else {
        int r = wave - MROWS;
        int q = r / FTOT, f = r % FTOT;
        src = (f < FG) ? qg + (size_t)(q * FG + f) * D
                       : ql + (size_t)(q * FL + (f - FG)) * D;
        dst = Qn + (size_t)r * D;
    }

    // lane holds 8 contiguous elements [8*lane .. 8*lane+8)
    float4 v0 = ((const float4*)src)[2 * lane];
    float4 v1 = ((const float4*)src)[2 * lane + 1];
    float ss = v0.x*v0.x + v0.y*v0.y + v0.z*v0.z + v0.w*v0.w
             + v1.x*v1.x + v1.y*v1.y + v1.z*v1.z + v1.w*v1.w;
    #pragma unroll
    for (int off = 32; off > 0; off >>= 1) ss += __shfl_xor(ss, off, 64);
    float scale = 1.0f / fmaxf(sqrtf(ss), 1e-12f);

    int w0 = __builtin_amdgcn_cvt_pk_fp8_f32(v0.x * scale, v0.y * scale, 0, false);
    w0     = __builtin_amdgcn_cvt_pk_fp8_f32(v0.z * scale, v0.w * scale, w0, true);
    int w1 = __builtin_amdgcn_cvt_pk_fp8_f32(v1.x * scale, v1.y * scale, 0, false);
    w1     = __builtin_amdgcn_cvt_pk_fp8_f32(v1.z * scale, v1.w * scale, w1, true);
    ((int2*)dst)[lane] = make_int2(w0, w1);
}

// 160x160-tile fp8 NT GEMM, BK=128, 4 K-chunks. r0's PROVEN skeleton:
// single-buffered As+Bs staged via global_load_lds (XOR-swizzled), lockstep
// 2-barrier loop, 3 blocks/CU for cross-block stage/compute overlap.
// Compute only is changed: MX-scaled mfma_scale_f32_16x16x128_f8f6f4 with
// unit (e8m0=127) scales -- bit-identical math to non-scaled fp8 at 2.27x
// rate; 1 MFMA per chunk per 16x16 tile (was 4).
// Register discipline (the r1 failure): fragments are UNIONS so the two
// ds_read_b128 results ARE the MFMA operand pairs (no element inserts);
// af[5] held (40 VGPR), bf streamed per-j (8 VGPR); with acc (100) + addr
// ~160 total < 170 cap of (256,3) -> no spill.
// Epilogue: sum (1-sim)^2 -> fused class-mean logits via one atomic per wave.
__global__ __launch_bounds__(256, 3) void gemm_kernel(const u8* __restrict__ Sn,
                                                      const u8* __restrict__ Qn,
                                                      const int* __restrict__ labels,
                                                      const float* __restrict__ rcnt,
                                                      float* __restrict__ out) {
    __shared__ __align__(16) u8 As[160][128];   // 16B chunk c holds global chunk c^((r>>1)&7)
    __shared__ __align__(16) u8 Bs[160][128];

    const int bx = blockIdx.x;          // 0..99  (query groups, 2 per block)
    const int by = blockIdx.y;          // 0..12  (support groups, 2 per block)
    const int tid = threadIdx.x;
    const int lane = tid & 63;
    const int w = tid >> 6;
    const int lm = lane & 15;
    const int lq = lane >> 4;
    const int wr = w >> 1;              // which 80-row half (support)
    const int wc = w & 1;               // which 80-col half (query)

    floatx4 acc[5][5];
    #pragma unroll
    for (int i = 0; i < 5; ++i)
        #pragma unroll
        for (int j = 0; j < 5; ++j) acc[i][j] = (floatx4){0.f, 0.f, 0.f, 0.f};

    const u8* Sbase = Sn + (size_t)by * 160 * D;
    const u8* Qbase = Qn + (size_t)bx * 160 * D;

    // staging: waves 0,1 -> A; waves 2,3 -> B. 20 slabs of 8 rows (1 KB each).
    const u8* gsrc = (w < 2) ? Sbase : Qbase;
    u8* ldst = (w < 2) ? (u8*)As : (u8*)Bs;
    const int sl0 = (w & 1) * 10;
    const int grow = lane >> 3;         // row within 8-row slab
    const int gc = lane & 7;            // 16B slot-chunk within 128B row

    union frag { intx8 v; intx4 h[2]; };

    // Precompute per-lane LDS byte offsets (lane's 32B = global k-chunks
    // 2lq,2lq+1, stored at slot chunks (2lq)^s,(2lq+1)^s, s=(r>>1)&7).
    int aoff[5], boff[5];
    #pragma unroll
    for (int i = 0; i < 5; ++i) {
        const int ra = wr * 80 + i * 16 + lm;
        aoff[i] = ra * 128 + (((2 * lq) ^ ((ra >> 1) & 7)) * 16);
        const int rb = wc * 80 + i * 16 + lm;
        boff[i] = rb * 128 + (((2 * lq) ^ ((rb >> 1) & 7)) * 16);
    }

    #pragma unroll 1
    for (int kc = 0; kc < 4; ++kc) {
        const int k0 = kc * 128;
        __syncthreads();                // prev chunk's readers done
        #pragma unroll
        for (int t = 0; t < 10; ++t) {
            const int sl = sl0 + t;
            const int r = sl * 8 + grow;
            const int cp = gc ^ ((r >> 1) & 7);
            gload_lds16(gsrc + (size_t)r * D + k0 + cp * 16, ldst + sl * 1024);
        }
        __syncthreads();                // drains vmcnt (global_load_lds) too

        frag af[5];
        #pragma unroll
        for (int i = 0; i < 5; ++i) {
            af[i].h[0] = *(const intx4*)((const u8*)As + aoff[i]);
            af[i].h[1] = *(const intx4*)((const u8*)As + (aoff[i] ^ 16));
        }
        #pragma unroll
        for (int j = 0; j < 5; ++j) {
            frag bf;
            bf.h[0] = *(const intx4*)((const u8*)Bs + boff[j]);
            bf.h[1] = *(const intx4*)((const u8*)Bs + (boff[j] ^ 16));
            #pragma unroll
            for (int i = 0; i < 5; ++i)
                acc[i][j] = __builtin_amdgcn_mfma_scale_f32_16x16x128_f8f6f4(
                    af[i].v, bf.v, acc[i][j], 0, 0,
                    0, 0x7F7F7F7F, 0, 0x7F7F7F7F);
        }
    }

    // Epilogue: sum (1-sim)^2 over the wave's 80x80 block, fuse class-mean.
    float local = 0.f;
    #pragma unroll
    for (int i = 0; i < 5; ++i)
        #pragma unroll
        for (int j = 0; j < 5; ++j)
            #pragma unroll
            for (int r = 0; r < 4; ++r) {
                const float d = 1.0f - acc[i][j][r];
                local = fmaf(d, d, local);
            }
    #pragma unroll
    for (int off = 32; off > 0; off >>= 1) local += __shfl_down(local, off, 64);

    const int sIdx = by * 2 + wr;       // 25 = pad group, dropped
    const int qIdx = bx * 2 + wc;
    if (lane == 0 && sIdx < NS) {
        const int c = labels[sIdx];
        atomicAdd(&out[qIdx * WAY + c], -2.0f * local * rcnt[c]);
    }
}

extern "C" void kernel_launch(void* const* d_in, const int* in_sizes, int n_in,
                              void* d_out, int out_size, void* d_ws, size_t ws_size,
                              hipStream_t stream) {
    const float* sg = (const float*)d_in[0];
    const float* sl = (const float*)d_in[1];
    const int* labels = (const int*)d_in[2];
    const float* qg = (const float*)d_in[3];
    const float* ql = (const float*)d_in[4];
    float* out = (float*)d_out;

    u8* Sn = (u8*)d_ws;                          // 2080*512 fp8 (padded)
    u8* Qn = Sn + (size_t)MPAD * D;              // 16000*512 fp8
    float* rcnt = (float*)(Qn + (size_t)NROWS * D);

    normalize_kernel<<<4501, 256, 0, stream>>>(sg, sl, qg, ql, Sn, Qn, labels, out, rcnt);
    dim3 g2(100, 13);
    gemm_kernel<<<g2, 256, 0, stream>>>(Sn, Qn, labels, rcnt, out);
}

// Round 4
// 111.082 us; speedup vs baseline: 1.2133x; 1.2133x over previous
//
#include <hip/hip_runtime.h>

#define NS 25
#define NQ 200
#define FG 16
#define FL 64
#define FTOT 80
#define D 512
#define WAY 5
#define MROWS 2000    // 25*80 support rows
#define MPAD 2080     // padded to 13 tiles of 160
#define NROWS 16000   // 200*80 query rows

typedef unsigned char u8;
typedef __attribute__((ext_vector_type(4))) float floatx4;
typedef __attribute__((ext_vector_type(4))) int intx4;

__device__ inline void gload_lds16(const void* g, void* l) {
    __builtin_amdgcn_global_load_lds(
        (const __attribute__((address_space(1))) unsigned int*)g,
        (__attribute__((address_space(3))) unsigned int*)l, 16, 0, 0);
}

// 4 rows per wave: 8 independent dwordx4 loads (128B/lane in flight) and 4
// independent shuffle-reduce chains interleaved -> latency-hiding via ILP
// (the old 1-row/wave version ran at 1.3 TB/s: 32B/lane + one dependent
// reduce chain = latency-bound). Math per row is bit-identical.
// Block 1125: zero Sn pad rows + zero out[] + per-class 1/count.
__global__ __launch_bounds__(256) void normalize_kernel(
        const float* __restrict__ sg, const float* __restrict__ sl,
        const float* __restrict__ qg, const float* __restrict__ ql,
        u8* __restrict__ Sn, u8* __restrict__ Qn,
        const int* __restrict__ labels,
        float* __restrict__ out, float* __restrict__ rcnt) {
    if (blockIdx.x == 1125) {
        intx4 z = {0, 0, 0, 0};
        intx4* pad = (intx4*)(Sn + (size_t)MROWS * D);   // 80 rows * 512 B = 2560 intx4
        for (int i = threadIdx.x; i < (MPAD - MROWS) * D / 16; i += 256) pad[i] = z;
        for (int i = threadIdx.x; i < NQ * WAY; i += 256) out[i] = 0.f;
        if (threadIdx.x == 0) {
            int counts[WAY] = {0, 0, 0, 0, 0};
            for (int s = 0; s < NS; ++s) counts[labels[s]]++;
            for (int c = 0; c < WAY; ++c) rcnt[c] = 1.0f / (float)(counts[c] ? counts[c] : 1);
        }
        return;
    }
    const int wv = (blockIdx.x * blockDim.x + threadIdx.x) >> 6;   // 0..4499
    const int lane = threadIdx.x & 63;
    const int row0 = wv * 4;

    const float* srcs[4];
    u8* dsts[4];
    #pragma unroll
    for (int k = 0; k < 4; ++k) {
        const int row = row0 + k;
        if (row < MROWS) {
            const int s = row / FTOT, f = row % FTOT;
            srcs[k] = (f < FG) ? sg + (size_t)(s * FG + f) * D
                               : sl + (size_t)(s * FL + (f - FG)) * D;
            dsts[k] = Sn + (size_t)row * D;
        } else {
            const int r = row - MROWS;
            const int q = r / FTOT, f = r % FTOT;
            srcs[k] = (f < FG) ? qg + (size_t)(q * FG + f) * D
                               : ql + (size_t)(q * FL + (f - FG)) * D;
            dsts[k] = Qn + (size_t)r * D;
        }
    }

    // lane holds 8 contiguous elements [8*lane .. 8*lane+8) of each row
    float4 va[4], vb[4];
    #pragma unroll
    for (int k = 0; k < 4; ++k) {
        va[k] = ((const float4*)srcs[k])[2 * lane];
        vb[k] = ((const float4*)srcs[k])[2 * lane + 1];
    }

    float ss[4];
    #pragma unroll
    for (int k = 0; k < 4; ++k)
        ss[k] = va[k].x*va[k].x + va[k].y*va[k].y + va[k].z*va[k].z + va[k].w*va[k].w
              + vb[k].x*vb[k].x + vb[k].y*vb[k].y + vb[k].z*vb[k].z + vb[k].w*vb[k].w;

    // 4 independent butterfly chains, interleaved per level
    #pragma unroll
    for (int off = 32; off > 0; off >>= 1) {
        #pragma unroll
        for (int k = 0; k < 4; ++k) ss[k] += __shfl_xor(ss[k], off, 64);
    }

    #pragma unroll
    for (int k = 0; k < 4; ++k) {
        const float scale = 1.0f / fmaxf(sqrtf(ss[k]), 1e-12f);
        int w0 = __builtin_amdgcn_cvt_pk_fp8_f32(va[k].x * scale, va[k].y * scale, 0, false);
        w0     = __builtin_amdgcn_cvt_pk_fp8_f32(va[k].z * scale, va[k].w * scale, w0, true);
        int w1 = __builtin_amdgcn_cvt_pk_fp8_f32(vb[k].x * scale, vb[k].y * scale, 0, false);
        w1     = __builtin_amdgcn_cvt_pk_fp8_f32(vb[k].z * scale, vb[k].w * scale, w1, true);
        ((int2*)dsts[k])[lane] = make_int2(w0, w1);
    }
}

// 160x160-tile fp8 NT GEMM aligned to 80-row groups; BK=128, XOR-swizzled LDS.
// 4 waves 2x2, each owns one 80x80 (s,q) block = 5x5 MFMA 16x16x32 fp8 tiles.
// (r0 kernel verbatim -- measured ~32 us. The MX-scaled variants spilled:
// r3 showed 34 MB scratch WRITE_SIZE at VGPR_Count=84. Non-scaled 16x16x32
// keeps fragments at 2 VGPR each -> fits the 170-cap of (256,3), no spill.)
// Epilogue: sum (1-sim)^2 -> fused class-mean logits via one atomic per wave.
__global__ __launch_bounds__(256, 3) void gemm_kernel(const u8* __restrict__ Sn,
                                                      const u8* __restrict__ Qn,
                                                      const int* __restrict__ labels,
                                                      const float* __restrict__ rcnt,
                                                      float* __restrict__ out) {
    __shared__ u8 As[160][128];   // fp8, BK=128; 16B chunk c holds global chunk c^((r>>1)&7)
    __shared__ u8 Bs[160][128];

    const int bx = blockIdx.x;          // 0..99  (query groups, 2 per block)
    const int by = blockIdx.y;          // 0..12  (support groups, 2 per block)
    const int tid = threadIdx.x;
    const int lane = tid & 63;
    const int w = tid >> 6;
    const int lm = lane & 15;
    const int lq = lane >> 4;
    const int wr = w >> 1;              // which 80-row half
    const int wc = w & 1;               // which 80-col half

    floatx4 acc[5][5];
    #pragma unroll
    for (int i = 0; i < 5; ++i)
        #pragma unroll
        for (int j = 0; j < 5; ++j) acc[i][j] = (floatx4){0.f, 0.f, 0.f, 0.f};

    const u8* Sbase = Sn + (size_t)by * 160 * D;
    const u8* Qbase = Qn + (size_t)bx * 160 * D;

    // staging: waves 0,1 -> A; waves 2,3 -> B. 20 slabs of 8 rows (1 KB each).
    const u8* gsrc = (w < 2) ? Sbase : Qbase;
    u8* ldst = (w < 2) ? (u8*)As : (u8*)Bs;
    const int sl0 = (w & 1) * 10;
    const int grow = lane >> 3;         // row within 8-row slab
    const int gc = lane & 7;            // 16B slot-chunk within 128B row

    // fragment read indices: lane reads 8B at k-chunk c' = ks*2+(lq>>1),
    // stored in slot chunk c'^((r>>1)&7), byte offset (lq&1)*8
    #pragma unroll 1
    for (int kc = 0; kc < 4; ++kc) {
        const int k0 = kc * 128;
        __syncthreads();                // prev chunk's readers done
        #pragma unroll
        for (int t = 0; t < 10; ++t) {
            const int sl = sl0 + t;
            const int r = sl * 8 + grow;
            const int cp = gc ^ ((r >> 1) & 7);
            gload_lds16(gsrc + (size_t)r * D + k0 + cp * 16, ldst + sl * 1024);
        }
        __syncthreads();                // drains vmcnt (global_load_lds) too
        #pragma unroll
        for (int ks = 0; ks < 4; ++ks) {
            long long a[5], b[5];
            #pragma unroll
            for (int i = 0; i < 5; ++i) {
                const int r = wr * 80 + i * 16 + lm;
                const int c = (ks * 2 + (lq >> 1)) ^ ((r >> 1) & 7);
                a[i] = *(const long long*)(&As[r][c * 16 + (lq & 1) * 8]);
            }
            #pragma unroll
            for (int j = 0; j < 5; ++j) {
                const int r = wc * 80 + j * 16 + lm;
                const int c = (ks * 2 + (lq >> 1)) ^ ((r >> 1) & 7);
                b[j] = *(const long long*)(&Bs[r][c * 16 + (lq & 1) * 8]);
            }
            #pragma unroll
            for (int i = 0; i < 5; ++i)
                #pragma unroll
                for (int j = 0; j < 5; ++j)
                    acc[i][j] = __builtin_amdgcn_mfma_f32_16x16x32_fp8_fp8(a[i], b[j], acc[i][j], 0, 0, 0);
        }
    }

    // Epilogue: sum (1-sim)^2 over the wave's 80x80 block, fuse class-mean.
    float local = 0.f;
    #pragma unroll
    for (int i = 0; i < 5; ++i)
        #pragma unroll
        for (int j = 0; j < 5; ++j)
            #pragma unroll
            for (int r = 0; r < 4; ++r) {
                const float d = 1.0f - acc[i][j][r];
                local = fmaf(d, d, local);
            }
    #pragma unroll
    for (int off = 32; off > 0; off >>= 1) local += __shfl_down(local, off, 64);

    const int sIdx = by * 2 + wr;       // 25 = pad group, dropped
    const int qIdx = bx * 2 + wc;
    if (lane == 0 && sIdx < NS) {
        const int c = labels[sIdx];
        atomicAdd(&out[qIdx * WAY + c], -2.0f * local * rcnt[c]);
    }
}

extern "C" void kernel_launch(void* const* d_in, const int* in_sizes, int n_in,
                              void* d_out, int out_size, void* d_ws, size_t ws_size,
                              hipStream_t stream) {
    const float* sg = (const float*)d_in[0];
    const float* sl = (const float*)d_in[1];
    const int* labels = (const int*)d_in[2];
    const float* qg = (const float*)d_in[3];
    const float* ql = (const float*)d_in[4];
    float* out = (float*)d_out;

    u8* Sn = (u8*)d_ws;                          // 2080*512 fp8 (padded)
    u8* Qn = Sn + (size_t)MPAD * D;              // 16000*512 fp8
    float* rcnt = (float*)(Qn + (size_t)NROWS * D);

    normalize_kernel<<<1126, 256, 0, stream>>>(sg, sl, qg, ql, Sn, Qn, labels, out, rcnt);
    dim3 g2(100, 13);
    gemm_kernel<<<g2, 256, 0, stream>>>(Sn, Qn, labels, rcnt, out);
}